// Round 17
// baseline (125.667 us; speedup 1.0000x reference)
//
#include <hip/hip_runtime.h>
#include <hip/hip_bf16.h>

// ddstgcn via conv/diffusion commutation:
//   y = proj0(x) + bias + sum_s A_s @ ( p1_s(x) + A_s @ p2_s(x) )
// K0 xpose  : x[b,c,v,l] f32 -> xq[b][l][v][48] bf16
// K1 proj_x : 7 projections as MFMA GEMM -> P1, P2, proj0 (all bf16, coalesced)
// K2 a2bt   : A f32 -> Abt[z][kt][v][32] bf16 (K-TILED; contiguous-read stream)
// K3 gemm_t : T := P1 + A_s @ P2 (in-place over P1), A from Abt (contiguous DMA)
// K4 gemm_yp: Ypart[z] = A_s @ T_s (bf16)
// K5 reduce : y = bias + proj0 + sum_s Ypart[s]
//
// Round-16: cold-A fetch was DRAM page-miss bound (128B per 2048B row per visit
// -> 1.8 TB/s, vs 5 TB/s contiguous). a2bt re-tiles A so every GEMM stage op is
// a contiguous 1KB DMA from a contiguous 8KB panel. A bytes halve (bf16), K-loop
// cvt disappears, both GEMMs share Abt. Bank swizzle (c ^ (r&3) ^ ((r>>2)&3))
// applied to BOTH sides of A and X staging (kills the 1.77M 8-way conflicts).

typedef unsigned short u16;
typedef u16 u16x4 __attribute__((ext_vector_type(4)));
typedef u16 u16x8 __attribute__((ext_vector_type(8)));
typedef __bf16 bf16x8 __attribute__((ext_vector_type(8)));
typedef float f32x4 __attribute__((ext_vector_type(4)));

#define GLD_LDS16(g, l)  __builtin_amdgcn_global_load_lds( \
    (const __attribute__((address_space(1))) void*)(g),    \
    (__attribute__((address_space(3))) void*)(l), 16, 0, 0)

__device__ __forceinline__ u16 f2bf(float f) {
    unsigned int u = __float_as_uint(f);
    u += 0x7fffu + ((u >> 16) & 1u);   // RNE
    return (u16)(u >> 16);
}
__device__ __forceinline__ float bf2f(u16 h) {
    return __uint_as_float(((unsigned int)h) << 16);
}

// ---------------- K0: x[b,c,v,l] f32 -> xq[b][l][v][48] bf16 ----------------
__global__ __launch_bounds__(256) void xpose(const float* __restrict__ x,
                                             u16* __restrict__ xq)
{
    const int t = threadIdx.x, vloc = t & 63, cg = t >> 6;
    const int v = blockIdx.x * 64 + vloc, b = blockIdx.y;

    u16 vals[12][12];
    #pragma unroll
    for (int ci = 0; ci < 12; ++ci) {
        int c = cg * 12 + ci;
        if (c < 40) {
            const float* xp = x + ((size_t)(b * 40 + c) * 512 + v) * 12;
            float4 f0 = *(const float4*)xp;
            float4 f1 = *(const float4*)(xp + 4);
            float4 f2 = *(const float4*)(xp + 8);
            vals[0][ci] = f2bf(f0.x);  vals[1][ci] = f2bf(f0.y);
            vals[2][ci] = f2bf(f0.z);  vals[3][ci] = f2bf(f0.w);
            vals[4][ci] = f2bf(f1.x);  vals[5][ci] = f2bf(f1.y);
            vals[6][ci] = f2bf(f1.z);  vals[7][ci] = f2bf(f1.w);
            vals[8][ci] = f2bf(f2.x);  vals[9][ci] = f2bf(f2.y);
            vals[10][ci] = f2bf(f2.z); vals[11][ci] = f2bf(f2.w);
        } else {
            #pragma unroll
            for (int l = 0; l < 12; ++l) vals[l][ci] = 0;
        }
    }
    #pragma unroll
    for (int l = 0; l < 12; ++l) {
        u16* dst = xq + ((size_t)(b * 12 + l) * 512 + v) * 48 + cg * 12;
        u16x4 a = { vals[l][0], vals[l][1], vals[l][2], vals[l][3] };
        u16x4 c4 = { vals[l][4], vals[l][5], vals[l][6], vals[l][7] };
        u16x4 d = { vals[l][8], vals[l][9], vals[l][10], vals[l][11] };
        *(u16x4*)(dst) = a;
        *(u16x4*)(dst + 4) = c4;
        *(u16x4*)(dst + 8) = d;
    }
}

// ---------------- K1: fused 7-way projection of x ----------------
__global__ __launch_bounds__(256) void proj_x(
    const u16* __restrict__ xq, const float* __restrict__ W,
    u16* __restrict__ P1, u16* __restrict__ P2, u16* __restrict__ proj0)
{
    __shared__ u16 sA[144 * 104];
    __shared__ u16 sB[2][2 * 64 * 48];

    const int t = threadIdx.x, lane = t & 63, wid = t >> 6;
    const int b = blockIdx.y, v0 = blockIdx.x * 64;

    for (int id = t; id < 144 * 5; id += 256) {
        int m = id / 5, c0 = (id % 5) * 8;
        u16x8 e = {}, o8 = {};
        if (m < 140) {
            int o = m % 20, sg = m / 20;
            const float* wp = W + o * 560 + sg * 80 + c0 * 2;
            float4 a = *(const float4*)wp;
            float4 bb = *(const float4*)(wp + 4);
            float4 c = *(const float4*)(wp + 8);
            float4 d = *(const float4*)(wp + 12);
            e[0] = f2bf(a.x);  o8[0] = f2bf(a.y);  e[1] = f2bf(a.z);  o8[1] = f2bf(a.w);
            e[2] = f2bf(bb.x); o8[2] = f2bf(bb.y); e[3] = f2bf(bb.z); o8[3] = f2bf(bb.w);
            e[4] = f2bf(c.x);  o8[4] = f2bf(c.y);  e[5] = f2bf(c.z);  o8[5] = f2bf(c.w);
            e[6] = f2bf(d.x);  o8[6] = f2bf(d.y);  e[7] = f2bf(d.z);  o8[7] = f2bf(d.w);
        }
        *(u16x8*)(&sA[m * 104 + c0]) = e;
        *(u16x8*)(&sA[m * 104 + 40 + c0]) = o8;
    }
    for (int id = t; id < 144 * 3; id += 256) {
        int m = id / 3, k0 = 80 + (id % 3) * 8;
        u16x8 z = {};
        *(u16x8*)(&sA[m * 104 + k0]) = z;
    }

    auto stage = [&](int l, int buf) {
        u16* dst = &sB[buf][0];
        #pragma unroll
        for (int i = 0; i < 3; ++i) {
            int op = wid * 3 + i;
            int tap = op / 6, rem = op % 6;
            const u16* src = xq + ((size_t)(b * 12 + l + 2 * tap) * 512 + v0) * 48
                             + rem * 512 + lane * 8;
            GLD_LDS16(src, dst + tap * 3072 + rem * 512);
        }
    };

    stage(0, 0);
    __syncthreads();

    const int lr = lane & 15, q = lane >> 4;
    bf16x8 af[9][3];
    #pragma unroll
    for (int mf = 0; mf < 9; ++mf)
        #pragma unroll
        for (int s = 0; s < 3; ++s)
            af[mf][s] = *(const bf16x8*)(&sA[(mf * 16 + lr) * 104 + s * 32 + q * 8]);

    const int voff = (wid * 16 + lr) * 48;
    int boff[3];
    #pragma unroll
    for (int s = 0; s < 3; ++s) {
        int k = s * 32 + q * 8;
        int tap, c;
        if (k < 40)      { tap = 0; c = k; }
        else if (k < 80) { tap = 1; c = k - 40; }
        else             { tap = 1; c = 40; }
        boff[s] = tap * 3072 + voff + c;
    }

    const int v = v0 + wid * 16 + lr;
    for (int l = 0; l < 10; ++l) {
        const int cur = l & 1;
        if (l < 9) stage(l + 1, cur ^ 1);

        const u16* bb = &sB[cur][0];
        bf16x8 xf[3];
        #pragma unroll
        for (int s = 0; s < 3; ++s) xf[s] = *(const bf16x8*)(bb + boff[s]);

        f32x4 acc[9] = {};
        #pragma unroll
        for (int s = 0; s < 3; ++s)
            #pragma unroll
            for (int mf = 0; mf < 9; ++mf)
                acc[mf] = __builtin_amdgcn_mfma_f32_16x16x32_bf16(
                    af[mf][s], xf[s], acc[mf], 0, 0, 0);

        #pragma unroll
        for (int mf = 0; mf < 9; ++mf)
            #pragma unroll
            for (int i = 0; i < 4; ++i) {
                int m = mf * 16 + q * 4 + i;
                if (m < 140) {
                    int o = m % 20, sg = m / 20;
                    float val = acc[mf][i];
                    if (sg == 0) {
                        proj0[((size_t)(b * 20 + o) * 10 + l) * 512 + v] = f2bf(val);
                    } else {
                        int s2 = (sg - 1) >> 1;
                        u16* dst = ((sg - 1) & 1) ? P2 : P1;
                        dst[((size_t)(s2 * 32 + b) * 200 + o * 10 + l) * 512 + v] = f2bf(val);
                    }
                }
            }
        __syncthreads();
    }
}

// ---------------- K2: A f32 -> Abt[z][kt][v][32] bf16 (K-tiled) ----------------
// block = (vgroup 64, z). Reads: each wave streams a contiguous 32KB segment
// (lane covers 512B contiguous). Writes: 64B contiguous per (thread, kt-chunk).
__global__ __launch_bounds__(256) void a2bt(
    const float* __restrict__ A0, const float* __restrict__ A1,
    const float* __restrict__ A2, u16* __restrict__ Abt)
{
    const int vg = blockIdx.x, z = blockIdx.y;     // 8 x 96
    const int s = z >> 5, b = z & 31;
    const float* src = (s == 0 ? A0 : (s == 1 ? A1 : A2))
                       + (size_t)b * 262144 + (size_t)vg * 64 * 512;
    const int t = threadIdx.x;
    const int row = t >> 2, seg = t & 3;           // thread owns A[row][seg*128..+128]
    const float* p = src + row * 512 + seg * 128;
    u16* dbase = Abt + (size_t)z * 16 * 16384 + (size_t)(vg * 64 + row) * 32;

    #pragma unroll
    for (int kc = 0; kc < 4; ++kc) {
        const float* pp = p + kc * 32;
        float4 v0 = *(const float4*)(pp);
        float4 v1 = *(const float4*)(pp + 4);
        float4 v2 = *(const float4*)(pp + 8);
        float4 v3 = *(const float4*)(pp + 12);
        float4 v4 = *(const float4*)(pp + 16);
        float4 v5 = *(const float4*)(pp + 20);
        float4 v6 = *(const float4*)(pp + 24);
        float4 v7 = *(const float4*)(pp + 28);
        u16x8 o0 = { f2bf(v0.x), f2bf(v0.y), f2bf(v0.z), f2bf(v0.w),
                     f2bf(v1.x), f2bf(v1.y), f2bf(v1.z), f2bf(v1.w) };
        u16x8 o1 = { f2bf(v2.x), f2bf(v2.y), f2bf(v2.z), f2bf(v2.w),
                     f2bf(v3.x), f2bf(v3.y), f2bf(v3.z), f2bf(v3.w) };
        u16x8 o2 = { f2bf(v4.x), f2bf(v4.y), f2bf(v4.z), f2bf(v4.w),
                     f2bf(v5.x), f2bf(v5.y), f2bf(v5.z), f2bf(v5.w) };
        u16x8 o3 = { f2bf(v6.x), f2bf(v6.y), f2bf(v6.z), f2bf(v6.w),
                     f2bf(v7.x), f2bf(v7.y), f2bf(v7.z), f2bf(v7.w) };
        const int kt = seg * 4 + kc;
        u16* d = dbase + (size_t)kt * 16384;
        *(u16x8*)(d)      = o0;
        *(u16x8*)(d + 8)  = o1;
        *(u16x8*)(d + 16) = o2;
        *(u16x8*)(d + 24) = o3;
    }
}

// swizzle helper: chunk permutation per row (involution, bank-spreading)
#define SWZ(r) (((r) & 3) ^ (((r) >> 2) & 3))

// ---------------- shared GEMM body: 2-phase DMA, 128v x 224c, Abt A ----------------
// BK=32, 16 K-steps, 4 waves (wave = 32v x 224c = 2 af x 14 xf = 28 MFMA/step).
// A from Abt: contiguous 8KB panel per (kt, vblk), 1KB per DMA op. All-bf16 LDS.
// EPI=0: T := acc + P1 (in-place RMW); EPI=1: plain bf16 store.
template <int EPI>
__device__ __forceinline__ void gemm_body(
    const u16* __restrict__ Abt,
    const u16* __restrict__ Xsrc, u16* __restrict__ Odst)
{
    __shared__ __align__(16) char smem[59136];
    u16* sA = (u16*)smem;                    // [2][128*32] u16 = 16 KB
    u16* sX = (u16*)(smem + 16384);          // [2][224*32] u16 = 28 KB

    // XCD swizzle: 384 blocks -> each XCD 48 eids = 12 whole z's
    const int bid = blockIdx.x;
    const int eid = (bid & 7) * 48 + (bid >> 3);
    const int z = eid >> 2;
    const int vblk = (eid & 3) * 128;

    const u16* Ab = Abt + (size_t)z * 16 * 16384;
    const u16* Xb = Xsrc + (size_t)z * 200 * 512;

    const int t = threadIdx.x;
    const int lane = t & 63, wid = t >> 6;
    const int lr = lane & 15, q = lane >> 4;

    auto stage = [&](int kt, int buf) {
        const int w0 = kt * 32;
        u16* ab = sA + buf * 4096;
        u16* xb = sX + buf * 7168;
        const u16* Asrc = Ab + (size_t)kt * 16384 + (size_t)vblk * 32;
        // A: 128 rows x 64B contiguous panel = 8 ops of 1KB; wave does 2.
        #pragma unroll
        for (int i = 0; i < 2; ++i) {
            int op = wid * 2 + i;
            int r  = op * 16 + (lane >> 2);
            int c  = lane & 3;
            GLD_LDS16(Asrc + r * 32 + ((c ^ SWZ(r)) * 8), ab + op * 512);
        }
        // X: 224 rows x 64B (row-strided source) = 14 ops of 1KB.
        #pragma unroll
        for (int i = 0; i < 4; ++i) {
            int op = wid + i * 4;
            if (op < 14) {
                int row = op * 16 + (lane >> 2);
                int c   = lane & 3;
                GLD_LDS16(Xb + (size_t)row * 512 + w0 + (c ^ SWZ(row)) * 8,
                          xb + op * 512);
            }
        }
    };

    f32x4 acc[14][2] = {};

    stage(0, 0);
    __syncthreads();

    for (int kt = 0; kt < 16; ++kt) {
        const int cur = kt & 1;
        if (kt < 15) stage(kt + 1, cur ^ 1);

        bf16x8 af[2];
        #pragma unroll
        for (int mf = 0; mf < 2; ++mf) {
            int r = wid * 32 + mf * 16 + lr;
            af[mf] = *(const bf16x8*)(sA + cur * 4096 + r * 32 + ((q ^ SWZ(r)) * 8));
        }
        #pragma unroll
        for (int cf = 0; cf < 14; ++cf) {
            int rx = cf * 16 + lr;
            bf16x8 xf = *(const bf16x8*)(sX + cur * 7168 + rx * 32 + ((q ^ SWZ(rx)) * 8));
            #pragma unroll
            for (int mf = 0; mf < 2; ++mf)
                acc[cf][mf] = __builtin_amdgcn_mfma_f32_16x16x32_bf16(
                    xf, af[mf], acc[cf][mf], 0, 0, 0);
        }
        __syncthreads();
    }

    // LDS-transpose epilogue: acc -> eb[col][v] (stride 132), coalesced u16x8 out.
    u16* eb = (u16*)smem;                    // 224*132*2 = 59136 B exactly
    #pragma unroll
    for (int cf = 0; cf < 14; ++cf)
        #pragma unroll
        for (int mf = 0; mf < 2; ++mf)
            #pragma unroll
            for (int i = 0; i < 4; ++i) {
                int col = cf * 16 + q * 4 + i;            // 0..223
                int vl  = wid * 32 + mf * 16 + lr;        // 0..127
                eb[col * 132 + vl] = f2bf(acc[cf][mf][i]);
            }
    __syncthreads();
    u16* Oz = Odst + (size_t)z * 200 * 512;
    for (int id = t; id < 224 * 16; id += 256) {
        int col = id >> 4, ch = id & 15;
        if (col < 200) {
            u16x8 tv = *(const u16x8*)(&eb[col * 132 + ch * 8]);
            size_t gidx = (size_t)col * 512 + vblk + ch * 8;
            if (EPI == 0) {
                u16x8 pv = *(const u16x8*)(Oz + gidx);
                u16x8 out;
                #pragma unroll
                for (int j = 0; j < 8; ++j) out[j] = f2bf(bf2f(tv[j]) + bf2f(pv[j]));
                *(u16x8*)(Oz + gidx) = out;
            } else {
                *(u16x8*)(Oz + gidx) = tv;
            }
        }
    }
}

__global__ __launch_bounds__(256) void gemm_t(
    const u16* __restrict__ Abt, const u16* __restrict__ P2, u16* __restrict__ T)
{
    gemm_body<0>(Abt, P2, T);
}

__global__ __launch_bounds__(256) void gemm_yp(
    const u16* __restrict__ Abt, const u16* __restrict__ T, u16* __restrict__ Ypart)
{
    gemm_body<1>(Abt, T, Ypart);
}

// ---------------- K5: y = bias + proj0 + sum_s Ypart[s] ----------------
__global__ __launch_bounds__(256) void reduce_y(
    const u16* __restrict__ Ypart, const u16* __restrict__ proj0,
    const float* __restrict__ bias, float* __restrict__ y)
{
    int i = blockIdx.x * 256 + threadIdx.x;   // over 32*20*512
    if (i >= 32 * 20 * 512) return;
    int v = i & 511;
    int r = i >> 9;                           // b*20 + o
    int o = r % 20, b = r / 20;
    float bb = bias[o];
    float* yp = y + ((size_t)r * 512 + v) * 10;
    #pragma unroll
    for (int l = 0; l < 10; ++l) {
        float sum = bb + bf2f(proj0[((size_t)r * 10 + l) * 512 + v]);
        #pragma unroll
        for (int s = 0; s < 3; ++s)
            sum += bf2f(Ypart[((size_t)(s * 32 + b) * 200 + o * 10 + l) * 512 + v]);
        yp[l] = sum;
    }
}

extern "C" void kernel_launch(void* const* d_in, const int* in_sizes, int n_in,
                              void* d_out, int out_size, void* d_ws, size_t ws_size,
                              hipStream_t stream) {
    const float* x    = (const float*)d_in[0];
    const float* A0   = (const float*)d_in[1];
    const float* A1   = (const float*)d_in[2];
    const float* A2   = (const float*)d_in[3];
    const float* W    = (const float*)d_in[4];
    const float* bias = (const float*)d_in[5];
    float* y = (float*)d_out;

    // ws (u16 elems): P1/T 9.83M | P2 9.83M (Ypart aliases after gemm_t) |
    // proj0 3.28M | tail: xq 9.44M then Abt 25.17M (xq dead before a2bt).
    // Total 48.1M u16 = 96.2 MB.
    const size_t PSZ = (size_t)96 * 200 * 512;
    u16* P1 = (u16*)d_ws;
    u16* P2 = P1 + PSZ;
    u16* proj0 = P2 + PSZ;
    u16* tail = proj0 + (size_t)32 * 20 * 10 * 512;
    u16* xq  = tail;
    u16* Abt = tail;
    u16* Ypart = P2;                          // alias: P2 dead after gemm_t

    xpose<<<dim3(8, 32), 256, 0, stream>>>(x, xq);
    proj_x<<<dim3(8, 32), 256, 0, stream>>>(xq, W, P1, P2, proj0);
    a2bt<<<dim3(8, 96), 256, 0, stream>>>(A0, A1, A2, Abt);   // clobbers xq (dead)
    gemm_t<<<dim3(384), 256, 0, stream>>>(Abt, P2, P1);       // T := P1 + A@P2
    gemm_yp<<<dim3(384), 256, 0, stream>>>(Abt, P1, Ypart);   // Ypart = A@T
    reduce_y<<<dim3(1280), 256, 0, stream>>>(Ypart, proj0, bias, y);
}

// Round 18
// 98.753 us; speedup vs baseline: 1.2725x; 1.2725x over previous
//
#include <hip/hip_runtime.h>
#include <hip/hip_bf16.h>

// ddstgcn via conv/diffusion commutation (FINAL = round-9 best, 99.2 us):
//   y = proj0(x) + bias + sum_s A_s @ ( p1_s(x) + A_s @ p2_s(x) )
// K0 xpose  : x[b,c,v,l] f32 -> xq[b][l][v][48] bf16
// K1 proj_x : 7 projections as MFMA GEMM -> P1, P2, proj0 (all bf16, coalesced)
// K2 gemm_t : T := P1 + A_s @ P2 (in-place over P1). 2-phase DMA f32-A staging,
//             LDS-transpose epilogue with coalesced u16x8 P1-add.
// K3 gemm_yp: Ypart[z] = A_s @ T_s (bf16, LDS-transpose coalesced stores).
// K4 reduce : y = bias + proj0 + sum_s Ypart[s].
//
// Measured ceiling notes (16 rounds): gemm_t is bound by the cold-A HBM read —
// 128B-per-2048B-row staging granule caps delivered BW at ~1.8-2.2 TB/s
// (contiguous streams reach ~4.7). All schedule/occupancy/relayout variants
// landed 99-126 us; this configuration is the measured optimum.

typedef unsigned short u16;
typedef u16 u16x4 __attribute__((ext_vector_type(4)));
typedef u16 u16x8 __attribute__((ext_vector_type(8)));
typedef __bf16 bf16x8 __attribute__((ext_vector_type(8)));
typedef float f32x4 __attribute__((ext_vector_type(4)));

#define GLD_LDS16(g, l)  __builtin_amdgcn_global_load_lds( \
    (const __attribute__((address_space(1))) void*)(g),    \
    (__attribute__((address_space(3))) void*)(l), 16, 0, 0)

__device__ __forceinline__ u16 f2bf(float f) {
    unsigned int u = __float_as_uint(f);
    u += 0x7fffu + ((u >> 16) & 1u);   // RNE
    return (u16)(u >> 16);
}
__device__ __forceinline__ float bf2f(u16 h) {
    return __uint_as_float(((unsigned int)h) << 16);
}

// ---------------- K0: x[b,c,v,l] f32 -> xq[b][l][v][48] bf16 ----------------
__global__ __launch_bounds__(256) void xpose(const float* __restrict__ x,
                                             u16* __restrict__ xq)
{
    const int t = threadIdx.x, vloc = t & 63, cg = t >> 6;
    const int v = blockIdx.x * 64 + vloc, b = blockIdx.y;

    u16 vals[12][12];
    #pragma unroll
    for (int ci = 0; ci < 12; ++ci) {
        int c = cg * 12 + ci;
        if (c < 40) {
            const float* xp = x + ((size_t)(b * 40 + c) * 512 + v) * 12;
            float4 f0 = *(const float4*)xp;
            float4 f1 = *(const float4*)(xp + 4);
            float4 f2 = *(const float4*)(xp + 8);
            vals[0][ci] = f2bf(f0.x);  vals[1][ci] = f2bf(f0.y);
            vals[2][ci] = f2bf(f0.z);  vals[3][ci] = f2bf(f0.w);
            vals[4][ci] = f2bf(f1.x);  vals[5][ci] = f2bf(f1.y);
            vals[6][ci] = f2bf(f1.z);  vals[7][ci] = f2bf(f1.w);
            vals[8][ci] = f2bf(f2.x);  vals[9][ci] = f2bf(f2.y);
            vals[10][ci] = f2bf(f2.z); vals[11][ci] = f2bf(f2.w);
        } else {
            #pragma unroll
            for (int l = 0; l < 12; ++l) vals[l][ci] = 0;
        }
    }
    #pragma unroll
    for (int l = 0; l < 12; ++l) {
        u16* dst = xq + ((size_t)(b * 12 + l) * 512 + v) * 48 + cg * 12;
        u16x4 a = { vals[l][0], vals[l][1], vals[l][2], vals[l][3] };
        u16x4 c4 = { vals[l][4], vals[l][5], vals[l][6], vals[l][7] };
        u16x4 d = { vals[l][8], vals[l][9], vals[l][10], vals[l][11] };
        *(u16x4*)(dst) = a;
        *(u16x4*)(dst + 4) = c4;
        *(u16x4*)(dst + 8) = d;
    }
}

// ---------------- K1: fused 7-way projection of x ----------------
__global__ __launch_bounds__(256) void proj_x(
    const u16* __restrict__ xq, const float* __restrict__ W,
    u16* __restrict__ P1, u16* __restrict__ P2, u16* __restrict__ proj0)
{
    __shared__ u16 sA[144 * 104];
    __shared__ u16 sB[2][2 * 64 * 48];

    const int t = threadIdx.x, lane = t & 63, wid = t >> 6;
    const int b = blockIdx.y, v0 = blockIdx.x * 64;

    for (int id = t; id < 144 * 5; id += 256) {
        int m = id / 5, c0 = (id % 5) * 8;
        u16x8 e = {}, o8 = {};
        if (m < 140) {
            int o = m % 20, sg = m / 20;
            const float* wp = W + o * 560 + sg * 80 + c0 * 2;
            float4 a = *(const float4*)wp;
            float4 bb = *(const float4*)(wp + 4);
            float4 c = *(const float4*)(wp + 8);
            float4 d = *(const float4*)(wp + 12);
            e[0] = f2bf(a.x);  o8[0] = f2bf(a.y);  e[1] = f2bf(a.z);  o8[1] = f2bf(a.w);
            e[2] = f2bf(bb.x); o8[2] = f2bf(bb.y); e[3] = f2bf(bb.z); o8[3] = f2bf(bb.w);
            e[4] = f2bf(c.x);  o8[4] = f2bf(c.y);  e[5] = f2bf(c.z);  o8[5] = f2bf(c.w);
            e[6] = f2bf(d.x);  o8[6] = f2bf(d.y);  e[7] = f2bf(d.z);  o8[7] = f2bf(d.w);
        }
        *(u16x8*)(&sA[m * 104 + c0]) = e;
        *(u16x8*)(&sA[m * 104 + 40 + c0]) = o8;
    }
    for (int id = t; id < 144 * 3; id += 256) {
        int m = id / 3, k0 = 80 + (id % 3) * 8;
        u16x8 z = {};
        *(u16x8*)(&sA[m * 104 + k0]) = z;
    }

    auto stage = [&](int l, int buf) {
        u16* dst = &sB[buf][0];
        #pragma unroll
        for (int i = 0; i < 3; ++i) {
            int op = wid * 3 + i;
            int tap = op / 6, rem = op % 6;
            const u16* src = xq + ((size_t)(b * 12 + l + 2 * tap) * 512 + v0) * 48
                             + rem * 512 + lane * 8;
            GLD_LDS16(src, dst + tap * 3072 + rem * 512);
        }
    };

    stage(0, 0);
    __syncthreads();

    const int lr = lane & 15, q = lane >> 4;
    bf16x8 af[9][3];
    #pragma unroll
    for (int mf = 0; mf < 9; ++mf)
        #pragma unroll
        for (int s = 0; s < 3; ++s)
            af[mf][s] = *(const bf16x8*)(&sA[(mf * 16 + lr) * 104 + s * 32 + q * 8]);

    const int voff = (wid * 16 + lr) * 48;
    int boff[3];
    #pragma unroll
    for (int s = 0; s < 3; ++s) {
        int k = s * 32 + q * 8;
        int tap, c;
        if (k < 40)      { tap = 0; c = k; }
        else if (k < 80) { tap = 1; c = k - 40; }
        else             { tap = 1; c = 40; }
        boff[s] = tap * 3072 + voff + c;
    }

    const int v = v0 + wid * 16 + lr;
    for (int l = 0; l < 10; ++l) {
        const int cur = l & 1;
        if (l < 9) stage(l + 1, cur ^ 1);

        const u16* bb = &sB[cur][0];
        bf16x8 xf[3];
        #pragma unroll
        for (int s = 0; s < 3; ++s) xf[s] = *(const bf16x8*)(bb + boff[s]);

        f32x4 acc[9] = {};
        #pragma unroll
        for (int s = 0; s < 3; ++s)
            #pragma unroll
            for (int mf = 0; mf < 9; ++mf)
                acc[mf] = __builtin_amdgcn_mfma_f32_16x16x32_bf16(
                    af[mf][s], xf[s], acc[mf], 0, 0, 0);

        #pragma unroll
        for (int mf = 0; mf < 9; ++mf)
            #pragma unroll
            for (int i = 0; i < 4; ++i) {
                int m = mf * 16 + q * 4 + i;
                if (m < 140) {
                    int o = m % 20, sg = m / 20;
                    float val = acc[mf][i];
                    if (sg == 0) {
                        proj0[((size_t)(b * 20 + o) * 10 + l) * 512 + v] = f2bf(val);
                    } else {
                        int s2 = (sg - 1) >> 1;
                        u16* dst = ((sg - 1) & 1) ? P2 : P1;
                        dst[((size_t)(s2 * 32 + b) * 200 + o * 10 + l) * 512 + v] = f2bf(val);
                    }
                }
            }
        __syncthreads();
    }
}

// ---------------- shared GEMM body: 2-phase DMA double-buffer ----------------
// tile 128v x 112col, BK=32, 16 K-steps, 4 waves (wave = 32v x 112col).
// LDS-transpose epilogue for both: EPI=0 adds P1 (in-place RMW); EPI=1 plain store.
template <int EPI>
__device__ __forceinline__ void gemm_body(
    const float* __restrict__ A0, const float* __restrict__ A1, const float* __restrict__ A2,
    const u16* __restrict__ Xsrc, u16* __restrict__ Odst)
{
    __shared__ float sAf[2][128 * 32];   // A f32, rows of 128B, chunk-XOR swizzled (32KB)
    __shared__ u16   sXs[2][112 * 32];   // X bf16, rows of 64B, linear (14KB)

    // XCD swizzle: 768 blocks -> XCD gets 96 consecutive eids = 12 whole z's
    const int bid = blockIdx.x;
    const int eid = (bid & 7) * 96 + (bid >> 3);
    const int z = eid >> 3, rem = eid & 7;
    const int vblk = (rem >> 1) * 128;
    const int colbase = (rem & 1) * 112;
    const int s = z >> 5, b = z & 31;

    const float* Af = (s == 0 ? A0 : (s == 1 ? A1 : A2)) + (size_t)b * 512 * 512;
    const u16* Xb = Xsrc + (size_t)z * 200 * 512;

    const int t = threadIdx.x;
    const int lane = t & 63, wid = t >> 6;
    const int lr = lane & 15, q = lane >> 4;
    const int kc0 = q * 2;                     // A chunk pair base (16B chunks)

    auto stage = [&](int kt, int buf) {
        const int w0 = kt * 32;
        float* ab = &sAf[buf][0];
        u16*   xb = &sXs[buf][0];
        #pragma unroll
        for (int i = 0; i < 4; ++i) {
            int op  = wid * 4 + i;
            int row = op * 8 + (lane >> 3);
            int pc  = lane & 7;
            const float* src = Af + (size_t)(vblk + row) * 512 + w0 + ((pc ^ (row & 7)) << 2);
            GLD_LDS16(src, ab + op * 256);
        }
        #pragma unroll
        for (int i = 0; i < 2; ++i) {
            int op = wid + i * 4;
            if (op < 7) {
                int row = op * 16 + (lane >> 2);
                int ch  = lane & 3;
                const u16* src = Xb + (size_t)(colbase + row) * 512 + w0 + ch * 8;
                GLD_LDS16(src, xb + op * 512);
            }
        }
    };

    f32x4 acc[7][2] = {};

    stage(0, 0);
    __syncthreads();

    for (int kt = 0; kt < 16; ++kt) {
        const int cur = kt & 1;
        if (kt < 15) stage(kt + 1, cur ^ 1);

        bf16x8 af[2];
        #pragma unroll
        for (int mf = 0; mf < 2; ++mf) {
            int r = wid * 32 + mf * 16 + lr;
            const float* rb = &sAf[cur][r * 32];
            f32x4 a0 = *(const f32x4*)(rb + ((kc0 ^ (r & 7)) << 2));
            f32x4 a1 = *(const f32x4*)(rb + (((kc0 + 1) ^ (r & 7)) << 2));
            union { u16x8 u; bf16x8 bv; } cv;
            cv.u = (u16x8){ f2bf(a0[0]), f2bf(a0[1]), f2bf(a0[2]), f2bf(a0[3]),
                            f2bf(a1[0]), f2bf(a1[1]), f2bf(a1[2]), f2bf(a1[3]) };
            af[mf] = cv.bv;
        }
        #pragma unroll
        for (int cf = 0; cf < 7; ++cf) {
            bf16x8 xf = *(const bf16x8*)(&sXs[cur][(cf * 16 + lr) * 32 + q * 8]);
            #pragma unroll
            for (int mf = 0; mf < 2; ++mf)
                acc[cf][mf] = __builtin_amdgcn_mfma_f32_16x16x32_bf16(
                    xf, af[mf], acc[cf][mf], 0, 0, 0);
        }
        __syncthreads();
    }

    // LDS-transpose epilogue: acc -> eb[col][v] (stride 140, bank-clean),
    // then coalesced u16x8 stores (EPI=0: += P1 in-place; EPI=1: plain).
    u16* eb = (u16*)&sAf[0][0];              // 112*140*2 = 31360 B <= 32 KB region
    #pragma unroll
    for (int cf = 0; cf < 7; ++cf)
        #pragma unroll
        for (int mf = 0; mf < 2; ++mf)
            #pragma unroll
            for (int i = 0; i < 4; ++i) {
                int col = cf * 16 + q * 4 + i;            // 0..111
                int vl  = wid * 32 + mf * 16 + lr;        // 0..127
                eb[col * 140 + vl] = f2bf(acc[cf][mf][i]);
            }
    __syncthreads();
    u16* Oz = Odst + (size_t)z * 200 * 512;
    for (int id = t; id < 112 * 16; id += 256) {
        int col = id >> 4, ch = id & 15;
        int rg = colbase + col;
        if (rg < 200) {
            u16x8 tv = *(const u16x8*)(&eb[col * 140 + ch * 8]);
            size_t gidx = (size_t)rg * 512 + vblk + ch * 8;
            if (EPI == 0) {
                u16x8 pv = *(const u16x8*)(Oz + gidx);
                u16x8 out;
                #pragma unroll
                for (int j = 0; j < 8; ++j) out[j] = f2bf(bf2f(tv[j]) + bf2f(pv[j]));
                *(u16x8*)(Oz + gidx) = out;
            } else {
                *(u16x8*)(Oz + gidx) = tv;
            }
        }
    }
}

__global__ __launch_bounds__(256) void gemm_t(
    const float* __restrict__ A0, const float* __restrict__ A1, const float* __restrict__ A2,
    const u16* __restrict__ P2, u16* __restrict__ T)
{
    gemm_body<0>(A0, A1, A2, P2, T);
}

__global__ __launch_bounds__(256) void gemm_yp(
    const float* __restrict__ A0, const float* __restrict__ A1, const float* __restrict__ A2,
    const u16* __restrict__ T, u16* __restrict__ Ypart)
{
    gemm_body<1>(A0, A1, A2, T, Ypart);
}

// ---------------- K4: y = bias + proj0 + sum_s Ypart[s] ----------------
__global__ __launch_bounds__(256) void reduce_y(
    const u16* __restrict__ Ypart, const u16* __restrict__ proj0,
    const float* __restrict__ bias, float* __restrict__ y)
{
    int i = blockIdx.x * 256 + threadIdx.x;   // over 32*20*512
    if (i >= 32 * 20 * 512) return;
    int v = i & 511;
    int r = i >> 9;                           // b*20 + o
    int o = r % 20, b = r / 20;
    float bb = bias[o];
    float* yp = y + ((size_t)r * 512 + v) * 10;
    #pragma unroll
    for (int l = 0; l < 10; ++l) {
        float sum = bb + bf2f(proj0[((size_t)r * 10 + l) * 512 + v]);
        #pragma unroll
        for (int s = 0; s < 3; ++s)
            sum += bf2f(Ypart[((size_t)(s * 32 + b) * 200 + o * 10 + l) * 512 + v]);
        yp[l] = sum;
    }
}

extern "C" void kernel_launch(void* const* d_in, const int* in_sizes, int n_in,
                              void* d_out, int out_size, void* d_ws, size_t ws_size,
                              hipStream_t stream) {
    const float* x    = (const float*)d_in[0];
    const float* A0   = (const float*)d_in[1];
    const float* A1   = (const float*)d_in[2];
    const float* A2   = (const float*)d_in[3];
    const float* W    = (const float*)d_in[4];
    const float* bias = (const float*)d_in[5];
    float* y = (float*)d_out;

    // ws (all bf16): P1/T 19.66MB | P2 19.66MB | proj0 6.55MB | Ypart 19.66MB
    // xq (18.87MB) aliases Ypart (dead before gemm_yp). Total 65.5MB.
    const size_t PSZ = (size_t)96 * 200 * 512;
    u16* P1 = (u16*)d_ws;
    u16* P2 = P1 + PSZ;
    u16* proj0 = P2 + PSZ;
    u16* Ypart = proj0 + (size_t)32 * 20 * 10 * 512;
    u16* xq = Ypart;                          // alias

    xpose<<<dim3(8, 32), 256, 0, stream>>>(x, xq);
    proj_x<<<dim3(8, 32), 256, 0, stream>>>(xq, W, P1, P2, proj0);
    gemm_t<<<dim3(768), 256, 0, stream>>>(A0, A1, A2, P2, P1);       // T := P1 + A@P2
    gemm_yp<<<dim3(768), 256, 0, stream>>>(A0, A1, A2, P1, Ypart);   // Ypart = A@T
    reduce_y<<<dim3(1280), 256, 0, stream>>>(Ypart, proj0, bias, y);
}